// Round 1
// baseline (1364.808 us; speedup 1.0000x reference)
//
#include <hip/hip_runtime.h>

typedef unsigned short u16;
typedef __attribute__((ext_vector_type(4))) float f32x4;
typedef __attribute__((ext_vector_type(8))) short s16x8;

constexpr int N = 16, L = 2048, C = 1024, A = 1024;
constexpr int NL = N * L;

__device__ __forceinline__ u16 f2bf(float v) {
  unsigned u = __float_as_uint(v);
  return (u16)((u + 0x7FFFu + ((u >> 16) & 1u)) >> 16);
}
__device__ __forceinline__ float bf2f(u16 h) { return __uint_as_float(((unsigned)h) << 16); }
__device__ __forceinline__ void split1(float v, u16 &h, u16 &l) {
  h = f2bf(v);
  l = f2bf(v - bf2f(h));
}

// LDS tile [128][64] bf16, linear 64 elems/row, XOR-swizzle of 16B groups by row&7.
// Conflict-free for both staging writes and b128 fragment reads.
__device__ __forceinline__ int lofs(int r, int k) {
  return r * 64 + ((((k >> 3) ^ (r & 7)) & 7) << 3) + (k & 7);
}

// ---------------------------------------------------------------- split W
__global__ __launch_bounds__(256) void split_w(const float* __restrict__ Wk,
                                               const float* __restrict__ Wq,
                                               u16* __restrict__ Whi,
                                               u16* __restrict__ Wlo) {
  int i = (blockIdx.x * 256 + threadIdx.x) * 4;
  if (i >= A * C) return;
  float4 k = *(const float4*)&Wk[i];
  float4 q = *(const float4*)&Wq[i];
  ushort4 h, l;
  split1(k.x, h.x, l.x); split1(k.y, h.y, l.y); split1(k.z, h.z, l.z); split1(k.w, h.w, l.w);
  *(ushort4*)&Whi[i] = h; *(ushort4*)&Wlo[i] = l;
  split1(q.x, h.x, l.x); split1(q.y, h.y, l.y); split1(q.z, h.z, l.z); split1(q.w, h.w, l.w);
  *(ushort4*)&Whi[A * C + i] = h; *(ushort4*)&Wlo[A * C + i] = l;
}

// ------------------------------------------------------------- transpose x
// x [N][L][C] fp32 -> xT [N][C][L] bf16
__global__ __launch_bounds__(256) void transpose_x(const float* __restrict__ x,
                                                   u16* __restrict__ xT) {
  __shared__ u16 tile[64 * 68];
  const int n = blockIdx.z;
  const int l0 = blockIdx.x * 64;
  const int c0 = blockIdx.y * 64;
  const int t = threadIdx.x;
  const int cg = t & 15, r = t >> 4;
#pragma unroll
  for (int i = 0; i < 4; ++i) {
    int rr = r + i * 16;
    float4 v = *(const float4*)&x[((size_t)n * L + l0 + rr) * C + c0 + cg * 4];
    ushort4 h;
    h.x = f2bf(v.x); h.y = f2bf(v.y); h.z = f2bf(v.z); h.w = f2bf(v.w);
    *(ushort4*)&tile[rr * 68 + cg * 4] = h;
  }
  __syncthreads();
  const int l4 = (t & 15) * 4;
#pragma unroll
  for (int i = 0; i < 4; ++i) {
    int cc = (t >> 4) + i * 16;
    ushort4 o;
    o.x = tile[(l4 + 0) * 68 + cc];
    o.y = tile[(l4 + 1) * 68 + cc];
    o.z = tile[(l4 + 2) * 68 + cc];
    o.w = tile[(l4 + 3) * 68 + cc];
    *(ushort4*)&xT[((size_t)n * C + c0 + cc) * L + l0 + l4] = o;
  }
}

// ---------------------------------------------------- K/Q projection GEMM
// O[which][nl][a] = sum_c x[nl][c] * W[which][a][c]   (which 0=K(Wk), 1=Q(Wq))
// 3-pass hi/lo bf16 for ~fp32 accuracy. Output stored as hi/lo bf16 pairs.
__global__ __launch_bounds__(256) void gemm_kq(const float* __restrict__ x,
                                               const u16* __restrict__ Whi,
                                               const u16* __restrict__ Wlo,
                                               u16* __restrict__ Ohi,
                                               u16* __restrict__ Olo) {
  __shared__ u16 lAh[128 * 64], lAl[128 * 64], lBh[128 * 64], lBl[128 * 64];
  const int which = blockIdx.z;
  const int row0 = blockIdx.y * 128;  // nl
  const int col0 = blockIdx.x * 128;  // a
  const u16* Wh = Whi + (size_t)which * A * C;
  const u16* Wl = Wlo + (size_t)which * A * C;
  u16* Oh = Ohi + (size_t)which * NL * A;
  u16* Ol = Olo + (size_t)which * NL * A;
  const int t = threadIdx.x;
  const int lane = t & 63, w = t >> 6, wr = w >> 1, wc = w & 1;
  const int lr = lane & 15, lk = lane >> 4;
  const int cg = t & 15, rw = t >> 4;  // A staging (float4)
  const int g8 = t & 7, rb = t >> 3;   // B staging (16B bf16)
  f32x4 acc[4][4] = {};
  for (int kk = 0; kk < C; kk += 64) {
    __syncthreads();
#pragma unroll
    for (int i = 0; i < 8; ++i) {
      int r = rw + i * 16;
      float4 v = *(const float4*)&x[(size_t)(row0 + r) * C + kk + cg * 4];
      ushort4 h, l;
      split1(v.x, h.x, l.x); split1(v.y, h.y, l.y);
      split1(v.z, h.z, l.z); split1(v.w, h.w, l.w);
      *(ushort4*)&lAh[lofs(r, cg * 4)] = h;
      *(ushort4*)&lAl[lofs(r, cg * 4)] = l;
    }
#pragma unroll
    for (int i = 0; i < 4; ++i) {
      int r = rb + i * 32;
      *(uint4*)&lBh[lofs(r, g8 * 8)] = *(const uint4*)&Wh[(size_t)(col0 + r) * C + kk + g8 * 8];
      *(uint4*)&lBl[lofs(r, g8 * 8)] = *(const uint4*)&Wl[(size_t)(col0 + r) * C + kk + g8 * 8];
    }
    __syncthreads();
#pragma unroll
    for (int ks = 0; ks < 2; ++ks) {
      const int ko = ks * 32 + lk * 8;
      s16x8 ah[4], al[4];
#pragma unroll
      for (int mi = 0; mi < 4; ++mi) {
        int r = wr * 64 + mi * 16 + lr;
        ah[mi] = *(const s16x8*)&lAh[lofs(r, ko)];
        al[mi] = *(const s16x8*)&lAl[lofs(r, ko)];
      }
#pragma unroll
      for (int ni = 0; ni < 4; ++ni) {
        int c = wc * 64 + ni * 16 + lr;
        s16x8 bh = *(const s16x8*)&lBh[lofs(c, ko)];
        s16x8 bl = *(const s16x8*)&lBl[lofs(c, ko)];
#pragma unroll
        for (int mi = 0; mi < 4; ++mi) {
          acc[mi][ni] = __builtin_amdgcn_mfma_f32_16x16x32_bf16(ah[mi], bh, acc[mi][ni], 0, 0, 0);
          acc[mi][ni] = __builtin_amdgcn_mfma_f32_16x16x32_bf16(ah[mi], bl, acc[mi][ni], 0, 0, 0);
          acc[mi][ni] = __builtin_amdgcn_mfma_f32_16x16x32_bf16(al[mi], bh, acc[mi][ni], 0, 0, 0);
        }
      }
    }
  }
#pragma unroll
  for (int mi = 0; mi < 4; ++mi)
#pragma unroll
    for (int ni = 0; ni < 4; ++ni) {
      int r = row0 + wr * 64 + mi * 16 + lk * 4;
      int c = col0 + wc * 64 + ni * 16 + lr;
#pragma unroll
      for (int j = 0; j < 4; ++j) {
        u16 h, l;
        split1(acc[mi][ni][j], h, l);
        Oh[(size_t)(r + j) * A + c] = h;
        Ol[(size_t)(r + j) * A + c] = l;
      }
    }
}

// ------------------------------------------------------------ scores GEMM
// scores[zl][l][m] = sum_a K[n][l][a] * Q[n][m][a], 3-pass hi/lo, fp32 out.
__global__ __launch_bounds__(256) void gemm_scores(const u16* __restrict__ KQhi,
                                                   const u16* __restrict__ KQlo,
                                                   float* __restrict__ scores,
                                                   int n0) {
  __shared__ u16 lAh[128 * 64], lAl[128 * 64], lBh[128 * 64], lBl[128 * 64];
  const int n = n0 + blockIdx.z;
  const int row0 = blockIdx.y * 128;  // l
  const int col0 = blockIdx.x * 128;  // m
  const u16* Kh = KQhi;
  const u16* Kl = KQlo;
  const u16* Qh = KQhi + (size_t)NL * A;
  const u16* Ql = KQlo + (size_t)NL * A;
  const size_t base = (size_t)n * L;
  const int t = threadIdx.x;
  const int lane = t & 63, w = t >> 6, wr = w >> 1, wc = w & 1;
  const int lr = lane & 15, lk = lane >> 4;
  const int g8 = t & 7, rb = t >> 3;
  f32x4 acc[4][4] = {};
  for (int kk = 0; kk < A; kk += 64) {
    __syncthreads();
#pragma unroll
    for (int i = 0; i < 4; ++i) {
      int r = rb + i * 32;
      *(uint4*)&lAh[lofs(r, g8 * 8)] = *(const uint4*)&Kh[(base + row0 + r) * A + kk + g8 * 8];
      *(uint4*)&lAl[lofs(r, g8 * 8)] = *(const uint4*)&Kl[(base + row0 + r) * A + kk + g8 * 8];
      *(uint4*)&lBh[lofs(r, g8 * 8)] = *(const uint4*)&Qh[(base + col0 + r) * A + kk + g8 * 8];
      *(uint4*)&lBl[lofs(r, g8 * 8)] = *(const uint4*)&Ql[(base + col0 + r) * A + kk + g8 * 8];
    }
    __syncthreads();
#pragma unroll
    for (int ks = 0; ks < 2; ++ks) {
      const int ko = ks * 32 + lk * 8;
      s16x8 ah[4], al[4];
#pragma unroll
      for (int mi = 0; mi < 4; ++mi) {
        int r = wr * 64 + mi * 16 + lr;
        ah[mi] = *(const s16x8*)&lAh[lofs(r, ko)];
        al[mi] = *(const s16x8*)&lAl[lofs(r, ko)];
      }
#pragma unroll
      for (int ni = 0; ni < 4; ++ni) {
        int c = wc * 64 + ni * 16 + lr;
        s16x8 bh = *(const s16x8*)&lBh[lofs(c, ko)];
        s16x8 bl = *(const s16x8*)&lBl[lofs(c, ko)];
#pragma unroll
        for (int mi = 0; mi < 4; ++mi) {
          acc[mi][ni] = __builtin_amdgcn_mfma_f32_16x16x32_bf16(ah[mi], bh, acc[mi][ni], 0, 0, 0);
          acc[mi][ni] = __builtin_amdgcn_mfma_f32_16x16x32_bf16(ah[mi], bl, acc[mi][ni], 0, 0, 0);
          acc[mi][ni] = __builtin_amdgcn_mfma_f32_16x16x32_bf16(al[mi], bh, acc[mi][ni], 0, 0, 0);
        }
      }
    }
  }
  float* S = scores + (size_t)blockIdx.z * L * L;
#pragma unroll
  for (int mi = 0; mi < 4; ++mi)
#pragma unroll
    for (int ni = 0; ni < 4; ++ni) {
      int r = row0 + wr * 64 + mi * 16 + lk * 4;
      int c = col0 + wc * 64 + ni * 16 + lr;
#pragma unroll
      for (int j = 0; j < 4; ++j) S[(size_t)(r + j) * L + c] = acc[mi][ni][j];
    }
}

// --------------------------------------------------- column softmax stats
// softmax over axis=1 (l). Stats per (n, m): max over l and sum of exp.
__global__ __launch_bounds__(256) void stats_partial(const float* __restrict__ scores,
                                                     float2* __restrict__ pstats,
                                                     int n0) {
  const int zn = blockIdx.z, lc = blockIdx.y, mb = blockIdx.x;
  const int m = mb * 256 + threadIdx.x;
  const float* s = scores + ((size_t)zn * L + lc * 256) * L + m;
  float mx = -3.0e38f, sum = 0.f;
  for (int i = 0; i < 256; ++i) {
    float v = s[(size_t)i * L];
    float nm = fmaxf(mx, v);
    sum = sum * __expf(mx - nm) + __expf(v - nm);
    mx = nm;
  }
  pstats[((size_t)(n0 + zn) * L + m) * 8 + lc] = make_float2(mx, sum);
}

__global__ __launch_bounds__(256) void stats_merge(const float2* __restrict__ pstats,
                                                   float2* __restrict__ stats,
                                                   int n0) {
  const int gn = n0 + blockIdx.z;
  const int m = blockIdx.x * 256 + threadIdx.x;
  const float2* p = &pstats[((size_t)gn * L + m) * 8];
  float gm = -3.0e38f;
#pragma unroll
  for (int j = 0; j < 8; ++j) gm = fmaxf(gm, p[j].x);
  float gs = 0.f;
#pragma unroll
  for (int j = 0; j < 8; ++j) gs += p[j].y * __expf(p[j].x - gm);
  stats[(size_t)gn * L + m] = make_float2(gm, 1.f / gs);
}

// ------------------------------------------------------------ output GEMM
// out[n][l][c] = sum_m exp(scores[l][m]-max[m])*inv[m] * x[n][m][c]
// A = attn (exp fused into staging), B = xT rows (c, m-contiguous).
__global__ __launch_bounds__(256) void gemm_out(const float* __restrict__ scores,
                                                const float2* __restrict__ stats,
                                                const u16* __restrict__ xT,
                                                float* __restrict__ out,
                                                int n0) {
  __shared__ u16 lA[128 * 64], lB[128 * 64];
  const int zn = blockIdx.z;
  const int gn = n0 + zn;
  const int row0 = blockIdx.y * 128;  // l
  const int col0 = blockIdx.x * 128;  // c
  const float* S = scores + (size_t)zn * L * L;
  const float2* st = stats + (size_t)gn * L;
  const u16* XT = xT + (size_t)gn * C * L;
  const int t = threadIdx.x;
  const int lane = t & 63, w = t >> 6, wr = w >> 1, wc = w & 1;
  const int lr = lane & 15, lk = lane >> 4;
  const int cg = t & 15, rw = t >> 4;
  const int g8 = t & 7, rb = t >> 3;
  f32x4 acc[4][4] = {};
  for (int kk = 0; kk < L; kk += 64) {
    __syncthreads();
#pragma unroll
    for (int i = 0; i < 8; ++i) {
      int r = rw + i * 16;
      float4 v = *(const float4*)&S[(size_t)(row0 + r) * L + kk + cg * 4];
      int m = kk + cg * 4;
      float2 s0 = st[m], s1 = st[m + 1], s2 = st[m + 2], s3 = st[m + 3];
      ushort4 h;
      h.x = f2bf(__expf(v.x - s0.x) * s0.y);
      h.y = f2bf(__expf(v.y - s1.x) * s1.y);
      h.z = f2bf(__expf(v.z - s2.x) * s2.y);
      h.w = f2bf(__expf(v.w - s3.x) * s3.y);
      *(ushort4*)&lA[lofs(r, cg * 4)] = h;
    }
#pragma unroll
    for (int i = 0; i < 4; ++i) {
      int r = rb + i * 32;
      *(uint4*)&lB[lofs(r, g8 * 8)] = *(const uint4*)&XT[(size_t)(col0 + r) * L + kk + g8 * 8];
    }
    __syncthreads();
#pragma unroll
    for (int ks = 0; ks < 2; ++ks) {
      const int ko = ks * 32 + lk * 8;
      s16x8 a[4];
#pragma unroll
      for (int mi = 0; mi < 4; ++mi)
        a[mi] = *(const s16x8*)&lA[lofs(wr * 64 + mi * 16 + lr, ko)];
#pragma unroll
      for (int ni = 0; ni < 4; ++ni) {
        s16x8 b = *(const s16x8*)&lB[lofs(wc * 64 + ni * 16 + lr, ko)];
#pragma unroll
        for (int mi = 0; mi < 4; ++mi)
          acc[mi][ni] = __builtin_amdgcn_mfma_f32_16x16x32_bf16(a[mi], b, acc[mi][ni], 0, 0, 0);
      }
    }
  }
#pragma unroll
  for (int mi = 0; mi < 4; ++mi)
#pragma unroll
    for (int ni = 0; ni < 4; ++ni) {
      int r = row0 + wr * 64 + mi * 16 + lk * 4;
      int c = col0 + wc * 64 + ni * 16 + lr;
#pragma unroll
      for (int j = 0; j < 4; ++j)
        out[((size_t)gn * L + r + j) * C + c] = acc[mi][ni][j];
    }
}

// ----------------------------------------------------------------- launch
extern "C" void kernel_launch(void* const* d_in, const int* in_sizes, int n_in,
                              void* d_out, int out_size, void* d_ws, size_t ws_size,
                              hipStream_t stream) {
  const float* x = (const float*)d_in[0];
  const float* Wq = (const float*)d_in[1];
  const float* Wk = (const float*)d_in[2];
  float* out = (float*)d_out;

  char* ws = (char*)d_ws;
  size_t off = 0;
  auto alloc = [&](size_t bytes) -> void* {
    void* p = ws + off;
    off = (off + bytes + 255) & ~(size_t)255;
    return p;
  };
  u16* Whi = (u16*)alloc((size_t)2 * A * C * 2);
  u16* Wlo = (u16*)alloc((size_t)2 * A * C * 2);
  u16* KQhi = (u16*)alloc((size_t)2 * NL * A * 2);
  u16* KQlo = (u16*)alloc((size_t)2 * NL * A * 2);
  u16* xT = (u16*)alloc((size_t)N * C * L * 2);
  float2* pstats = (float2*)alloc((size_t)N * L * 8 * 8);
  float2* stats = (float2*)alloc((size_t)N * L * 8);
  const size_t fixed = off;
  const size_t per_n = (size_t)L * L * 4;
  int chunk = 1;
  if (ws_size > fixed + per_n) {
    size_t avail = (ws_size - fixed) / per_n;
    chunk = avail >= 16 ? 16 : (int)avail;
  }
  float* scores = (float*)alloc(per_n * (size_t)chunk);

  split_w<<<dim3(A * C / 4 / 256), dim3(256), 0, stream>>>(Wk, Wq, Whi, Wlo);
  transpose_x<<<dim3(L / 64, C / 64, N), dim3(256), 0, stream>>>(x, xT);
  gemm_kq<<<dim3(A / 128, NL / 128, 2), dim3(256), 0, stream>>>(x, Whi, Wlo, KQhi, KQlo);
  for (int n0 = 0; n0 < N; n0 += chunk) {
    int cn = (N - n0) < chunk ? (N - n0) : chunk;
    gemm_scores<<<dim3(L / 128, L / 128, cn), dim3(256), 0, stream>>>(KQhi, KQlo, scores, n0);
    stats_partial<<<dim3(L / 256, 8, cn), dim3(256), 0, stream>>>(scores, pstats, n0);
    stats_merge<<<dim3(L / 256, 1, cn), dim3(256), 0, stream>>>(pstats, stats, n0);
    gemm_out<<<dim3(C / 128, L / 128, cn), dim3(256), 0, stream>>>(scores, stats, xT, out, n0);
  }
}